// Round 15
// baseline (434.408 us; speedup 1.0000x reference)
//
#include <hip/hip_runtime.h>
#include <hip/hip_bf16.h>

// MultiheadAttention fused pipeline for MI355X (gfx950).
// B=2, S=4096, D=768, H=12, HD=64. fp32 inputs, fp32 output, bf16 compute.
// Round 15: attention reads V fragments DIRECTLY from global (contiguous
// thanks to the spos column permutation; L1-served across the block's 4
// waves) -- halves the DS-pipe load that bound R13 (295K->147K cyc/CU),
// putting K on LDS and V on the VMEM pipe in parallel. QB=64, 4-wave,
// grid 1536 (24 waves/CU). K staging/double-buffer unchanged.
// GEMMs/cvt unchanged from round 12.

#define B_ 2
#define S_ 4096
#define D_ 768
#define H_ 12
#define HD_ 64
#define TD_ (3 * D_)
#define QKD_ (2 * D_)   // qk buffer row stride

static constexpr float LOG2E = 1.4426950408889634f;
static constexpr float QSCL = 0.125f * LOG2E;

typedef __bf16 bf16x8 __attribute__((ext_vector_type(8)));
typedef unsigned short ushortx8 __attribute__((ext_vector_type(8)));
typedef unsigned short ushortx4 __attribute__((ext_vector_type(4)));
typedef float floatx4 __attribute__((ext_vector_type(4)));

__device__ inline unsigned short f2bf(float f) {
  return __builtin_bit_cast(unsigned short, (__bf16)f);  // native RNE cvt
}
__device__ inline float bf2f(unsigned short u) {
  return __uint_as_float(((unsigned int)u) << 16);
}
__device__ inline void glds16(const unsigned short* g, unsigned short* l) {
  __builtin_amdgcn_global_load_lds(
      (const __attribute__((address_space(1))) unsigned int*)g,
      (__attribute__((address_space(3))) unsigned int*)l, 16, 0, 0);
}

// ---------------------------------------------------------------------------
// fused fp32 -> bf16 convert of x, qkv_w, proj_w (one launch)
// ---------------------------------------------------------------------------
__global__ __launch_bounds__(256)
void cvt_all(const float* __restrict__ s0, unsigned short* __restrict__ d0, int n0,
             const float* __restrict__ s1, unsigned short* __restrict__ d1, int n1,
             const float* __restrict__ s2, unsigned short* __restrict__ d2, int n2) {
  int idx = blockIdx.x * 256 + threadIdx.x;
  const float* s; unsigned short* d;
  if (idx < n0) { s = s0; d = d0; }
  else if (idx < n0 + n1) { s = s1; d = d1; idx -= n0; }
  else if (idx < n0 + n1 + n2) { s = s2; d = d2; idx -= n0 + n1; }
  else return;
  floatx4 v = *reinterpret_cast<const floatx4*>(&s[(size_t)idx * 4]);
  ushortx4 o;
#pragma unroll
  for (int j = 0; j < 4; ++j) o[j] = f2bf(v[j]);
  *reinterpret_cast<ushortx4*>(&d[(size_t)idx * 4]) = o;
}

// ---------------------------------------------------------------------------
// bf16 GEMM: C[M,N] = A[M,K] @ W[N,K]^T + bias[N], fp32 accum.
// global_load_lds staging, source-pre-swizzled; linear LDS; NFR n-frags/wave.
// QKV_EPI: q cols (<D) -> qkbuf scaled by QSCL; k cols -> qkbuf;
// V cols -> vT [B,H,HD,S] column-permuted within 32-blocks.
// ---------------------------------------------------------------------------
template <int NFR, bool QKV_EPI>
__global__ __launch_bounds__(256)
void gemm_bf16(const unsigned short* __restrict__ A,
               const unsigned short* __restrict__ W,
               const float* __restrict__ bias,
               float* __restrict__ Cf,
               unsigned short* __restrict__ qkbuf,
               unsigned short* __restrict__ vT,
               int M, int N, int K) {
  constexpr int BM = 128, BN = NFR * 32, BK = 64;
  __shared__ __attribute__((aligned(16))) unsigned short As[BM][BK];
  __shared__ __attribute__((aligned(16))) unsigned short Ws[BN][BK];

  const int tid = threadIdx.x;
  const int lane = tid & 63;
  const int wid = tid >> 6;
  const int wm = wid >> 1;
  const int wn = wid & 1;
  const int m0 = blockIdx.y * BM;
  const int n0 = blockIdx.x * BN;
  const int lr = lane & 15;
  const int g = lane >> 4;
  const int e8 = lr & 7;
  const int ro = g * 4;
  const int srow = lane >> 3;
  const int sch = lane & 7;

  floatx4 acc[4][NFR];
#pragma unroll
  for (int m = 0; m < 4; ++m)
#pragma unroll
    for (int n = 0; n < NFR; ++n) acc[m][n] = (floatx4){0.f, 0.f, 0.f, 0.f};

  for (int kb = 0; kb < K; kb += BK) {
#pragma unroll
    for (int c = 0; c < 4; ++c) {
      int seg = wid * 4 + c;
      int row = seg * 8 + srow;
      glds16(&A[(size_t)(m0 + row) * K + kb + ((sch ^ srow) << 3)], &As[seg * 8][0]);
    }
#pragma unroll
    for (int c = 0; c < NFR; ++c) {
      int seg = wid * NFR + c;
      int row = seg * 8 + srow;
      glds16(&W[(size_t)(n0 + row) * K + kb + ((sch ^ srow) << 3)], &Ws[seg * 8][0]);
    }
    __syncthreads();

#pragma unroll
    for (int ks = 0; ks < 2; ++ks) {
      int ch = ((ks << 2) + g) ^ e8;
      bf16x8 af[4], bfr[NFR];
#pragma unroll
      for (int m = 0; m < 4; ++m)
        af[m] = *reinterpret_cast<const bf16x8*>(&As[wm * 64 + m * 16 + lr][ch << 3]);
#pragma unroll
      for (int n = 0; n < NFR; ++n)
        bfr[n] = *reinterpret_cast<const bf16x8*>(&Ws[wn * (NFR * 16) + n * 16 + lr][ch << 3]);
#pragma unroll
      for (int m = 0; m < 4; ++m)
#pragma unroll
        for (int n = 0; n < NFR; ++n)
          acc[m][n] = __builtin_amdgcn_mfma_f32_16x16x32_bf16(af[m], bfr[n], acc[m][n], 0, 0, 0);
    }
    __syncthreads();
  }

#pragma unroll
  for (int n = 0; n < NFR; ++n) {
    int col = n0 + wn * (NFR * 16) + n * 16 + lr;
    float bv = bias[col];
#pragma unroll
    for (int m = 0; m < 4; ++m) {
      int row = m0 + wm * 64 + m * 16 + ro;
      if constexpr (QKV_EPI) {
        if (col >= QKD_) {
          int dcol = col - QKD_;
          int hh = dcol >> 6, dd = dcol & 63;
          int bb = row >> 12, s = row & (S_ - 1);
          int s5 = s & 31;
          int spos = (s & ~31) + ((s5 >> 2) & 3) * 8 + ((s5 >> 4) & 1) * 4;
          ushortx4 o4;
#pragma unroll
          for (int i = 0; i < 4; ++i) o4[i] = f2bf(acc[m][n][i] + bv);
          *reinterpret_cast<ushortx4*>(
              &vT[(size_t)((bb * H_ + hh) * 64 + dd) * S_ + spos]) = o4;
        } else {
          const float scl = (col < D_) ? QSCL : 1.0f;  // pre-scale q columns
#pragma unroll
          for (int i = 0; i < 4; ++i)
            qkbuf[(size_t)(row + i) * QKD_ + col] = f2bf((acc[m][n][i] + bv) * scl);
        }
      } else {
#pragma unroll
        for (int i = 0; i < 4; ++i)
          Cf[(size_t)(row + i) * N + col] = acc[m][n][i] + bv;
      }
    }
  }
}

// ---------------------------------------------------------------------------
// Flash attention (swapped-QK^T, register P, no max, MFMA-ones denominator).
// QB=64, 4 waves, each wave owns one 16-row q-tile (grid 1536, 24 waves/CU).
// K tiles double-buffered in LDS (glds16); V fragments read DIRECTLY from
// global vT -- the spos permutation makes them contiguous 16B per lane, and
// all 4 waves read identical addresses per tile (L1-served). DS pipe load
// halves vs R13; V rides the parallel VMEM pipe.
// ---------------------------------------------------------------------------
__global__ __launch_bounds__(256)
void attn_kernel(const unsigned short* __restrict__ qkbuf,
                 const unsigned short* __restrict__ vT,
                 unsigned short* __restrict__ outb) {
  constexpr int QB = 64, KVB = 64, NT = S_ / KVB;
  __shared__ __attribute__((aligned(16))) unsigned short L[2 * 4096];  // K only

  const int tid = threadIdx.x;
  const int lane = tid & 63;
  const int wid = tid >> 6;
  const int q0 = blockIdx.x * QB;
  const int h = blockIdx.y;
  const int b = blockIdx.z;
  const int lr = lane & 15;
  const int g = lane >> 4;
  const int e8 = lr & 7;
  const int wq = wid * 16;       // wave's q-row offset (16 rows per wave)

  const unsigned short* Qg = qkbuf + (size_t)b * S_ * QKD_ + (size_t)h * HD_;
  const unsigned short* Kg = Qg + D_;
  const unsigned short* Vg = vT + (size_t)(b * H_ + h) * HD_ * S_;

  const int srow = lane >> 3;
  const int sch = lane & 7;

  // Q fragments (B-operand) — already scaled by 0.125*log2e in GEMM1
  bf16x8 qf[2];
#pragma unroll
  for (int ks = 0; ks < 2; ++ks)
    qf[ks] = *reinterpret_cast<const bf16x8*>(
        &Qg[(size_t)(q0 + wq + lr) * QKD_ + ks * 32 + g * 8]);

  // all-ones A-fragment for the denominator MFMA
  bf16x8 onesf;
#pragma unroll
  for (int j = 0; j < 8; ++j) onesf[j] = (__bf16)1.0f;

  floatx4 lacc = (floatx4){0.f, 0.f, 0.f, 0.f};
  floatx4 oacc[4];
#pragma unroll
  for (int dt = 0; dt < 4; ++dt) oacc[dt] = (floatx4){0.f, 0.f, 0.f, 0.f};

  // K fragment LDS offsets (shorts), computed once
  int koff[4][2];
#pragma unroll
  for (int kt = 0; kt < 4; ++kt)
#pragma unroll
    for (int ks = 0; ks < 2; ++ks)
      koff[kt][ks] = (kt * 16 + lr) * 64 + ((((ks << 2) + g) ^ e8) << 3);

  // V row pointers: vf[ks][dt] = 16B at vrow[dt] + kv0 + 32*ks
  const unsigned short* vrow[4];
#pragma unroll
  for (int dt = 0; dt < 4; ++dt)
    vrow[dt] = Vg + (size_t)(dt * 16 + lr) * S_ + 8 * g;
  int vco = 0;  // kv column offset, advances per tile

  const unsigned short* kp0 = Kg + (size_t)(wid * 16 + srow) * QKD_ + ((sch ^ srow) << 3);
  const unsigned short* kp1 = kp0 + (size_t)8 * QKD_;

#define STAGE(BUF) do { \
    glds16(kp0, &L[(BUF) * 4096 + (wid * 16) * 64]); \
    glds16(kp1, &L[(BUF) * 4096 + (wid * 16 + 8) * 64]); \
    kp0 += (size_t)KVB * QKD_; kp1 += (size_t)KVB * QKD_; } while (0)

#define COMPUTE(BUF) do { \
    bf16x8 kf[4][2], vf[2][4]; \
    _Pragma("unroll") \
    for (int kt = 0; kt < 4; ++kt) \
      _Pragma("unroll") \
      for (int ks = 0; ks < 2; ++ks) \
        kf[kt][ks] = *reinterpret_cast<const bf16x8*>(&L[(BUF) * 4096 + koff[kt][ks]]); \
    _Pragma("unroll") \
    for (int ks = 0; ks < 2; ++ks) \
      _Pragma("unroll") \
      for (int dt = 0; dt < 4; ++dt) \
        vf[ks][dt] = __builtin_bit_cast(bf16x8, \
            *reinterpret_cast<const ushortx8*>(&vrow[dt][vco + 32 * ks])); \
    floatx4 sc[4]; \
    _Pragma("unroll") \
    for (int kt = 0; kt < 4; ++kt) { \
      floatx4 c = (floatx4){0.f, 0.f, 0.f, 0.f}; \
      _Pragma("unroll") \
      for (int ks = 0; ks < 2; ++ks) \
        c = __builtin_amdgcn_mfma_f32_16x16x32_bf16(kf[kt][ks], qf[ks], c, 0, 0, 0); \
      sc[kt] = c; \
    } \
    _Pragma("unroll") \
    for (int kt = 0; kt < 4; ++kt) \
      _Pragma("unroll") \
      for (int i = 0; i < 4; ++i) \
        sc[kt][i] = __builtin_amdgcn_exp2f(sc[kt][i]); \
    bf16x8 pf0, pf1; \
    _Pragma("unroll") \
    for (int j = 0; j < 8; ++j) { \
      pf0[j] = (__bf16)sc[(j >> 2)][j & 3]; \
      pf1[j] = (__bf16)sc[2 + (j >> 2)][j & 3]; \
    } \
    lacc = __builtin_amdgcn_mfma_f32_16x16x32_bf16(onesf, pf0, lacc, 0, 0, 0); \
    lacc = __builtin_amdgcn_mfma_f32_16x16x32_bf16(onesf, pf1, lacc, 0, 0, 0); \
    _Pragma("unroll") \
    for (int dt = 0; dt < 4; ++dt) \
      oacc[dt] = __builtin_amdgcn_mfma_f32_16x16x32_bf16(vf[0][dt], pf0, oacc[dt], 0, 0, 0); \
    _Pragma("unroll") \
    for (int dt = 0; dt < 4; ++dt) \
      oacc[dt] = __builtin_amdgcn_mfma_f32_16x16x32_bf16(vf[1][dt], pf1, oacc[dt], 0, 0, 0); \
    vco += KVB; } while (0)

  STAGE(0);
  for (int t = 0; t < NT; t += 2) {
    __syncthreads();
    STAGE(1);
    COMPUTE(0);
    __syncthreads();
    if (t + 2 < NT) STAGE(0);
    COMPUTE(1);
  }
#undef STAGE
#undef COMPUTE

  // lacc rows are replicated column sums: l = Σ_k p[k][q]
  {
    float l = lacc[0];
    int q = q0 + wq + lr;
    float inv = __builtin_amdgcn_rcpf(l);
    size_t rowbase = ((size_t)b * S_ + q) * D_ + h * HD_;
#pragma unroll
    for (int dt = 0; dt < 4; ++dt) {
      ushortx4 o4;
#pragma unroll
      for (int i = 0; i < 4; ++i) o4[i] = f2bf(oacc[dt][i] * inv);
      *reinterpret_cast<ushortx4*>(&outb[rowbase + dt * 16 + 4 * g]) = o4;
    }
  }
}

// ---------------------------------------------------------------------------
extern "C" void kernel_launch(void* const* d_in, const int* in_sizes, int n_in,
                              void* d_out, int out_size, void* d_ws, size_t ws_size,
                              hipStream_t stream) {
  const float* x      = (const float*)d_in[0];
  const float* qkv_w  = (const float*)d_in[1];
  const float* qkv_b  = (const float*)d_in[2];
  const float* proj_w = (const float*)d_in[3];
  const float* proj_b = (const float*)d_in[4];
  float* out = (float*)d_out;

  unsigned short* qkbuf   = (unsigned short*)d_ws;
  unsigned short* vTbuf   = qkbuf + (size_t)B_ * S_ * QKD_;
  unsigned short* attnbuf = vTbuf + (size_t)B_ * H_ * HD_ * S_;
  unsigned short* xbf     = attnbuf + (size_t)B_ * S_ * D_;
  unsigned short* wqkvbf  = xbf + (size_t)B_ * S_ * D_;
  unsigned short* wprojbf = wqkvbf + (size_t)TD_ * D_;

  dim3 blk(256);
  const int nx = B_ * S_ * D_ / 4, nw1 = TD_ * D_ / 4, nw2 = D_ * D_ / 4;
  cvt_all<<<dim3((nx + nw1 + nw2 + 255) / 256), blk, 0, stream>>>(
      x, xbf, nx, qkv_w, wqkvbf, nw1, proj_w, wprojbf, nw2);

  gemm_bf16<4, true><<<dim3(TD_ / 128, (B_ * S_) / 128), blk, 0, stream>>>(
      xbf, wqkvbf, qkv_b, nullptr, qkbuf, vTbuf, B_ * S_, TD_, D_);

  attn_kernel<<<dim3(S_ / 64, H_, B_), blk, 0, stream>>>(qkbuf, vTbuf, attnbuf);

  gemm_bf16<2, false><<<dim3(D_ / 64, (B_ * S_) / 128), blk, 0, stream>>>(
      attnbuf, wprojbf, proj_b, out, nullptr, nullptr, B_ * S_, D_, D_);
}

// Round 16
// 187.455 us; speedup vs baseline: 2.3174x; 2.3174x over previous
//
#include <hip/hip_runtime.h>
#include <hip/hip_bf16.h>

// MultiheadAttention fused pipeline for MI355X (gfx950).
// B=2, S=4096, D=768, H=12, HD=64. fp32 inputs, fp32 output, bf16 compute.
// Round 16: REVERT to the round-12 proven best (187.4 us total).
// Attention: QB=128, NQT=2, 4 waves, flat-LDS double buffer, swapped-QK^T,
// register P, no max tracking, MFMA-ones denominator. V^T column-permuted
// in global by GEMM1 so all LDS traffic is conflict-free b128.
// R13-R15 established: QB=64 -> DS-pipe-bound (124us), NQT=4 -> TLP-starved
// (134us), V-via-VMEM -> scattered loads (385us). This config is the best
// total-time point of the structure.

#define B_ 2
#define S_ 4096
#define D_ 768
#define H_ 12
#define HD_ 64
#define TD_ (3 * D_)
#define QKD_ (2 * D_)   // qk buffer row stride

static constexpr float LOG2E = 1.4426950408889634f;
static constexpr float QSCL = 0.125f * LOG2E;

typedef __bf16 bf16x8 __attribute__((ext_vector_type(8)));
typedef unsigned short ushortx8 __attribute__((ext_vector_type(8)));
typedef unsigned short ushortx4 __attribute__((ext_vector_type(4)));
typedef float floatx4 __attribute__((ext_vector_type(4)));

__device__ inline unsigned short f2bf(float f) {
  return __builtin_bit_cast(unsigned short, (__bf16)f);  // native RNE cvt
}
__device__ inline float bf2f(unsigned short u) {
  return __uint_as_float(((unsigned int)u) << 16);
}
__device__ inline void glds16(const unsigned short* g, unsigned short* l) {
  __builtin_amdgcn_global_load_lds(
      (const __attribute__((address_space(1))) unsigned int*)g,
      (__attribute__((address_space(3))) unsigned int*)l, 16, 0, 0);
}

// ---------------------------------------------------------------------------
// fused fp32 -> bf16 convert of x, qkv_w, proj_w (one launch)
// ---------------------------------------------------------------------------
__global__ __launch_bounds__(256)
void cvt_all(const float* __restrict__ s0, unsigned short* __restrict__ d0, int n0,
             const float* __restrict__ s1, unsigned short* __restrict__ d1, int n1,
             const float* __restrict__ s2, unsigned short* __restrict__ d2, int n2) {
  int idx = blockIdx.x * 256 + threadIdx.x;
  const float* s; unsigned short* d;
  if (idx < n0) { s = s0; d = d0; }
  else if (idx < n0 + n1) { s = s1; d = d1; idx -= n0; }
  else if (idx < n0 + n1 + n2) { s = s2; d = d2; idx -= n0 + n1; }
  else return;
  floatx4 v = *reinterpret_cast<const floatx4*>(&s[(size_t)idx * 4]);
  ushortx4 o;
#pragma unroll
  for (int j = 0; j < 4; ++j) o[j] = f2bf(v[j]);
  *reinterpret_cast<ushortx4*>(&d[(size_t)idx * 4]) = o;
}

// ---------------------------------------------------------------------------
// bf16 GEMM: C[M,N] = A[M,K] @ W[N,K]^T + bias[N], fp32 accum.
// global_load_lds staging, source-pre-swizzled; linear LDS; NFR n-frags/wave.
// QKV_EPI: q cols (<D) -> qkbuf scaled by QSCL; k cols -> qkbuf;
// V cols -> vT [B,H,HD,S] column-permuted within 32-blocks.
// ---------------------------------------------------------------------------
template <int NFR, bool QKV_EPI>
__global__ __launch_bounds__(256)
void gemm_bf16(const unsigned short* __restrict__ A,
               const unsigned short* __restrict__ W,
               const float* __restrict__ bias,
               float* __restrict__ Cf,
               unsigned short* __restrict__ qkbuf,
               unsigned short* __restrict__ vT,
               int M, int N, int K) {
  constexpr int BM = 128, BN = NFR * 32, BK = 64;
  __shared__ __attribute__((aligned(16))) unsigned short As[BM][BK];
  __shared__ __attribute__((aligned(16))) unsigned short Ws[BN][BK];

  const int tid = threadIdx.x;
  const int lane = tid & 63;
  const int wid = tid >> 6;
  const int wm = wid >> 1;
  const int wn = wid & 1;
  const int m0 = blockIdx.y * BM;
  const int n0 = blockIdx.x * BN;
  const int lr = lane & 15;
  const int g = lane >> 4;
  const int e8 = lr & 7;
  const int ro = g * 4;
  const int srow = lane >> 3;
  const int sch = lane & 7;

  floatx4 acc[4][NFR];
#pragma unroll
  for (int m = 0; m < 4; ++m)
#pragma unroll
    for (int n = 0; n < NFR; ++n) acc[m][n] = (floatx4){0.f, 0.f, 0.f, 0.f};

  for (int kb = 0; kb < K; kb += BK) {
#pragma unroll
    for (int c = 0; c < 4; ++c) {
      int seg = wid * 4 + c;
      int row = seg * 8 + srow;
      glds16(&A[(size_t)(m0 + row) * K + kb + ((sch ^ srow) << 3)], &As[seg * 8][0]);
    }
#pragma unroll
    for (int c = 0; c < NFR; ++c) {
      int seg = wid * NFR + c;
      int row = seg * 8 + srow;
      glds16(&W[(size_t)(n0 + row) * K + kb + ((sch ^ srow) << 3)], &Ws[seg * 8][0]);
    }
    __syncthreads();

#pragma unroll
    for (int ks = 0; ks < 2; ++ks) {
      int ch = ((ks << 2) + g) ^ e8;
      bf16x8 af[4], bfr[NFR];
#pragma unroll
      for (int m = 0; m < 4; ++m)
        af[m] = *reinterpret_cast<const bf16x8*>(&As[wm * 64 + m * 16 + lr][ch << 3]);
#pragma unroll
      for (int n = 0; n < NFR; ++n)
        bfr[n] = *reinterpret_cast<const bf16x8*>(&Ws[wn * (NFR * 16) + n * 16 + lr][ch << 3]);
#pragma unroll
      for (int m = 0; m < 4; ++m)
#pragma unroll
        for (int n = 0; n < NFR; ++n)
          acc[m][n] = __builtin_amdgcn_mfma_f32_16x16x32_bf16(af[m], bfr[n], acc[m][n], 0, 0, 0);
    }
    __syncthreads();
  }

#pragma unroll
  for (int n = 0; n < NFR; ++n) {
    int col = n0 + wn * (NFR * 16) + n * 16 + lr;
    float bv = bias[col];
#pragma unroll
    for (int m = 0; m < 4; ++m) {
      int row = m0 + wm * 64 + m * 16 + ro;
      if constexpr (QKV_EPI) {
        if (col >= QKD_) {
          int dcol = col - QKD_;
          int hh = dcol >> 6, dd = dcol & 63;
          int bb = row >> 12, s = row & (S_ - 1);
          int s5 = s & 31;
          int spos = (s & ~31) + ((s5 >> 2) & 3) * 8 + ((s5 >> 4) & 1) * 4;
          ushortx4 o4;
#pragma unroll
          for (int i = 0; i < 4; ++i) o4[i] = f2bf(acc[m][n][i] + bv);
          *reinterpret_cast<ushortx4*>(
              &vT[(size_t)((bb * H_ + hh) * 64 + dd) * S_ + spos]) = o4;
        } else {
          const float scl = (col < D_) ? QSCL : 1.0f;  // pre-scale q columns
#pragma unroll
          for (int i = 0; i < 4; ++i)
            qkbuf[(size_t)(row + i) * QKD_ + col] = f2bf((acc[m][n][i] + bv) * scl);
        }
      } else {
#pragma unroll
        for (int i = 0; i < 4; ++i)
          Cf[(size_t)(row + i) * N + col] = acc[m][n][i] + bv;
      }
    }
  }
}

// ---------------------------------------------------------------------------
// Flash attention (swapped-QK^T, register P, no max, MFMA-ones denominator).
// R12-proven: QB=128 (2 q-tiles/wave), flat LDS double buffer,
// __syncthreads loop, offsets hoisted. Q pre-scaled by 0.125*log2e.
// ---------------------------------------------------------------------------
__global__ __launch_bounds__(256)
void attn_kernel(const unsigned short* __restrict__ qkbuf,
                 const unsigned short* __restrict__ vT,
                 unsigned short* __restrict__ outb) {
  constexpr int QB = 128, KVB = 64, NT = S_ / KVB;
  __shared__ __attribute__((aligned(16))) unsigned short L[2 * 8192];

  const int tid = threadIdx.x;
  const int lane = tid & 63;
  const int wid = tid >> 6;
  const int q0 = blockIdx.x * QB;
  const int h = blockIdx.y;
  const int b = blockIdx.z;
  const int lr = lane & 15;
  const int g = lane >> 4;
  const int e8 = lr & 7;
  const int wq = wid * 32;

  const unsigned short* Qg = qkbuf + (size_t)b * S_ * QKD_ + (size_t)h * HD_;
  const unsigned short* Kg = Qg + D_;
  const unsigned short* Vg = vT + (size_t)(b * H_ + h) * HD_ * S_;

  const int srow = lane >> 3;
  const int sch = lane & 7;

  // Q fragments (B-operand) — already scaled by 0.125*log2e in GEMM1
  bf16x8 qf[2][2];
#pragma unroll
  for (int qt = 0; qt < 2; ++qt)
#pragma unroll
    for (int ks = 0; ks < 2; ++ks)
      qf[qt][ks] = *reinterpret_cast<const bf16x8*>(
          &Qg[(size_t)(q0 + wq + qt * 16 + lr) * QKD_ + ks * 32 + g * 8]);

  // all-ones A-fragment for the denominator MFMA
  bf16x8 onesf;
#pragma unroll
  for (int j = 0; j < 8; ++j) onesf[j] = (__bf16)1.0f;

  floatx4 lacc[2] = {(floatx4){0.f, 0.f, 0.f, 0.f}, (floatx4){0.f, 0.f, 0.f, 0.f}};
  floatx4 oacc[2][4];
#pragma unroll
  for (int qt = 0; qt < 2; ++qt)
#pragma unroll
    for (int dt = 0; dt < 4; ++dt) oacc[qt][dt] = (floatx4){0.f, 0.f, 0.f, 0.f};

  // per-thread LDS fragment offsets (shorts), computed once
  int koff[4][2], voff[2][4];
#pragma unroll
  for (int kt = 0; kt < 4; ++kt)
#pragma unroll
    for (int ks = 0; ks < 2; ++ks)
      koff[kt][ks] = (kt * 16 + lr) * 64 + ((((ks << 2) + g) ^ e8) << 3);
#pragma unroll
  for (int ks = 0; ks < 2; ++ks)
#pragma unroll
    for (int dt = 0; dt < 4; ++dt)
      voff[ks][dt] = 4096 + (dt * 16 + lr) * 64 + ((((ks << 2) + g) ^ e8) << 3);

  const unsigned short* kp0 = Kg + (size_t)(wid * 16 + srow) * QKD_ + ((sch ^ srow) << 3);
  const unsigned short* kp1 = kp0 + (size_t)8 * QKD_;
  const unsigned short* vp0 = Vg + (size_t)(wid * 16 + srow) * S_ + ((sch ^ srow) << 3);
  const unsigned short* vp1 = vp0 + (size_t)8 * S_;

#define STAGE(BUF) do { \
    glds16(kp0, &L[(BUF) * 8192 + (wid * 16) * 64]); \
    glds16(kp1, &L[(BUF) * 8192 + (wid * 16 + 8) * 64]); \
    glds16(vp0, &L[(BUF) * 8192 + 4096 + (wid * 16) * 64]); \
    glds16(vp1, &L[(BUF) * 8192 + 4096 + (wid * 16 + 8) * 64]); \
    kp0 += (size_t)KVB * QKD_; kp1 += (size_t)KVB * QKD_; \
    vp0 += KVB; vp1 += KVB; } while (0)

#define COMPUTE(BUF) do { \
    bf16x8 kf[4][2], vf[2][4]; \
    _Pragma("unroll") \
    for (int kt = 0; kt < 4; ++kt) \
      _Pragma("unroll") \
      for (int ks = 0; ks < 2; ++ks) \
        kf[kt][ks] = *reinterpret_cast<const bf16x8*>(&L[(BUF) * 8192 + koff[kt][ks]]); \
    _Pragma("unroll") \
    for (int ks = 0; ks < 2; ++ks) \
      _Pragma("unroll") \
      for (int dt = 0; dt < 4; ++dt) \
        vf[ks][dt] = *reinterpret_cast<const bf16x8*>(&L[(BUF) * 8192 + voff[ks][dt]]); \
    _Pragma("unroll") \
    for (int qt = 0; qt < 2; ++qt) { \
      floatx4 sc[4]; \
      _Pragma("unroll") \
      for (int kt = 0; kt < 4; ++kt) { \
        floatx4 c = (floatx4){0.f, 0.f, 0.f, 0.f}; \
        _Pragma("unroll") \
        for (int ks = 0; ks < 2; ++ks) \
          c = __builtin_amdgcn_mfma_f32_16x16x32_bf16(kf[kt][ks], qf[qt][ks], c, 0, 0, 0); \
        sc[kt] = c; \
      } \
      _Pragma("unroll") \
      for (int kt = 0; kt < 4; ++kt) \
        _Pragma("unroll") \
        for (int i = 0; i < 4; ++i) \
          sc[kt][i] = __builtin_amdgcn_exp2f(sc[kt][i]); \
      bf16x8 pf0, pf1; \
      _Pragma("unroll") \
      for (int j = 0; j < 8; ++j) { \
        pf0[j] = (__bf16)sc[(j >> 2)][j & 3]; \
        pf1[j] = (__bf16)sc[2 + (j >> 2)][j & 3]; \
      } \
      lacc[qt] = __builtin_amdgcn_mfma_f32_16x16x32_bf16(onesf, pf0, lacc[qt], 0, 0, 0); \
      lacc[qt] = __builtin_amdgcn_mfma_f32_16x16x32_bf16(onesf, pf1, lacc[qt], 0, 0, 0); \
      _Pragma("unroll") \
      for (int dt = 0; dt < 4; ++dt) \
        oacc[qt][dt] = __builtin_amdgcn_mfma_f32_16x16x32_bf16(vf[0][dt], pf0, oacc[qt][dt], 0, 0, 0); \
      _Pragma("unroll") \
      for (int dt = 0; dt < 4; ++dt) \
        oacc[qt][dt] = __builtin_amdgcn_mfma_f32_16x16x32_bf16(vf[1][dt], pf1, oacc[qt][dt], 0, 0, 0); \
    } } while (0)

  STAGE(0);
  for (int t = 0; t < NT; t += 2) {
    __syncthreads();
    STAGE(1);
    COMPUTE(0);
    __syncthreads();
    if (t + 2 < NT) STAGE(0);
    COMPUTE(1);
  }
#undef STAGE
#undef COMPUTE

  // lacc rows are replicated column sums: l = Σ_k p[k][q]
#pragma unroll
  for (int qt = 0; qt < 2; ++qt) {
    float l = lacc[qt][0];
    int q = q0 + wq + qt * 16 + lr;
    float inv = __builtin_amdgcn_rcpf(l);
    size_t rowbase = ((size_t)b * S_ + q) * D_ + h * HD_;
#pragma unroll
    for (int dt = 0; dt < 4; ++dt) {
      ushortx4 o4;
#pragma unroll
      for (int i = 0; i < 4; ++i) o4[i] = f2bf(oacc[qt][dt][i] * inv);
      *reinterpret_cast<ushortx4*>(&outb[rowbase + dt * 16 + 4 * g]) = o4;
    }
  }
}

// ---------------------------------------------------------------------------
extern "C" void kernel_launch(void* const* d_in, const int* in_sizes, int n_in,
                              void* d_out, int out_size, void* d_ws, size_t ws_size,
                              hipStream_t stream) {
  const float* x      = (const float*)d_in[0];
  const float* qkv_w  = (const float*)d_in[1];
  const float* qkv_b  = (const float*)d_in[2];
  const float* proj_w = (const float*)d_in[3];
  const float* proj_b = (const float*)d_in[4];
  float* out = (float*)d_out;

  unsigned short* qkbuf   = (unsigned short*)d_ws;
  unsigned short* vTbuf   = qkbuf + (size_t)B_ * S_ * QKD_;
  unsigned short* attnbuf = vTbuf + (size_t)B_ * H_ * HD_ * S_;
  unsigned short* xbf     = attnbuf + (size_t)B_ * S_ * D_;
  unsigned short* wqkvbf  = xbf + (size_t)B_ * S_ * D_;
  unsigned short* wprojbf = wqkvbf + (size_t)TD_ * D_;

  dim3 blk(256);
  const int nx = B_ * S_ * D_ / 4, nw1 = TD_ * D_ / 4, nw2 = D_ * D_ / 4;
  cvt_all<<<dim3((nx + nw1 + nw2 + 255) / 256), blk, 0, stream>>>(
      x, xbf, nx, qkv_w, wqkvbf, nw1, proj_w, wprojbf, nw2);

  gemm_bf16<4, true><<<dim3(TD_ / 128, (B_ * S_) / 128), blk, 0, stream>>>(
      xbf, wqkvbf, qkv_b, nullptr, qkbuf, vTbuf, B_ * S_, TD_, D_);

  attn_kernel<<<dim3(S_ / 128, H_, B_), blk, 0, stream>>>(qkbuf, vTbuf, attnbuf);

  gemm_bf16<2, false><<<dim3(D_ / 64, (B_ * S_) / 128), blk, 0, stream>>>(
      attnbuf, wprojbf, proj_b, out, nullptr, nullptr, B_ * S_, D_, D_);
}